// Round 1
// baseline (591.789 us; speedup 1.0000x reference)
//
#include <hip/hip_runtime.h>
#include <stdint.h>
#include <stddef.h>

#define N_NODES   40000
#define N_EDGES   640000
#define IN_FEATS  256
#define EDGE_FEATS 64
#define OUT_FEATS 128
#define NUM_HEADS 8
#define HD        16   // per-head dim

typedef __attribute__((ext_vector_type(8))) short  short8;   // 8 x bf16 bits
typedef __attribute__((ext_vector_type(4))) float  floatx4;

__device__ inline short f2bf(float f) {
  union { float f; uint32_t u; } v; v.f = f;
  uint32_t r = v.u + 0x7fffu + ((v.u >> 16) & 1u);   // RNE
  return (short)(r >> 16);
}

__device__ inline short8 cvt8(float4 lo, float4 hi) {
  short8 r;
  r[0] = f2bf(lo.x); r[1] = f2bf(lo.y); r[2] = f2bf(lo.z); r[3] = f2bf(lo.w);
  r[4] = f2bf(hi.x); r[5] = f2bf(hi.y); r[6] = f2bf(hi.z); r[7] = f2bf(hi.w);
  return r;
}

// ---------------- K1: fold edge_w/edge_b with a_e -> Wfold[8][64], bfold[8]
__global__ __launch_bounds__(512) void fold_kernel(
    const float* __restrict__ edge_w, const float* __restrict__ edge_b,
    const float* __restrict__ attn, float* __restrict__ Wfold,
    float* __restrict__ bfold) {
  int t = threadIdx.x;            // 512 = 8 heads * 64 feats
  int h = t >> 6, k = t & 63;
  float s = 0.f;
  #pragma unroll
  for (int d = 0; d < HD; d++)
    s += edge_w[(h * HD + d) * EDGE_FEATS + k] * attn[h * 48 + 32 + d];
  Wfold[h * EDGE_FEATS + k] = s;
  if (k == 0) {
    float b = 0.f;
    #pragma unroll
    for (int d = 0; d < HD; d++)
      b += edge_b[h * HD + d] * attn[h * 48 + 32 + d];
    bfold[h] = b;
  }
}

// ---------------- K2: Wh = node_feats @ node_w^T + node_b  (bf16 MFMA)
// one wave computes a 16(M) x 128(N) strip; K=256 in 8 steps of 32
__global__ __launch_bounds__(256) void wh_gemm(
    const float* __restrict__ A,     // node_feats [40000][256]
    const float* __restrict__ W,     // node_w [128][256] (K-major, = B^T)
    const float* __restrict__ bias,  // node_b [128]
    float* __restrict__ Wh) {        // [40000][128]
  int wave = (blockIdx.x * blockDim.x + threadIdx.x) >> 6;
  int lane = threadIdx.x & 63;
  int m0 = wave * 16;
  if (m0 >= N_NODES) return;
  int row = lane & 15, quad = lane >> 4;

  floatx4 acc[8];
  #pragma unroll
  for (int nt = 0; nt < 8; nt++) acc[nt] = (floatx4)(0.f);

  const float4* A4 = (const float4*)A;
  const float4* W4 = (const float4*)W;
  int a_base = ((m0 + row) * IN_FEATS + quad * 8) >> 2;   // in float4 units

  #pragma unroll
  for (int s = 0; s < 8; s++) {
    float4 alo = A4[a_base + s * 8];
    float4 ahi = A4[a_base + s * 8 + 1];
    short8 af = cvt8(alo, ahi);
    #pragma unroll
    for (int nt = 0; nt < 8; nt++) {
      int b_base = ((nt * 16 + row) * IN_FEATS + s * 32 + quad * 8) >> 2;
      float4 blo = W4[b_base];
      float4 bhi = W4[b_base + 1];
      short8 bf = cvt8(blo, bhi);
      acc[nt] = __builtin_amdgcn_mfma_f32_16x16x32_bf16(af, bf, acc[nt], 0, 0, 0);
    }
  }
  // epilogue: C/D layout col = lane&15 (n within tile), row = quad*4 + reg (m)
  #pragma unroll
  for (int nt = 0; nt < 8; nt++) {
    int n = nt * 16 + row;
    float b = bias[n];
    #pragma unroll
    for (int r = 0; r < 4; r++) {
      int m = m0 + quad * 4 + r;
      Wh[m * OUT_FEATS + n] = acc[nt][r] + b;
    }
  }
}

// ---------------- K3: s_src[n][h], s_dst[n][h] from Wh
__global__ __launch_bounds__(256) void ssd_kernel(
    const float* __restrict__ Wh, const float* __restrict__ attn,
    float* __restrict__ s_src, float* __restrict__ s_dst) {
  int t = blockIdx.x * blockDim.x + threadIdx.x;   // 320000 threads
  if (t >= N_NODES * NUM_HEADS) return;
  int n = t >> 3, h = t & 7;
  const float4* w4 = (const float4*)(Wh + (size_t)n * OUT_FEATS + h * HD);
  const float* as = attn + h * 48;
  const float* ad = attn + h * 48 + 16;
  float ss = 0.f, sd = 0.f;
  #pragma unroll
  for (int j = 0; j < 4; j++) {
    float4 w = w4[j];
    ss += w.x * as[j*4] + w.y * as[j*4+1] + w.z * as[j*4+2] + w.w * as[j*4+3];
    sd += w.x * ad[j*4] + w.y * ad[j*4+1] + w.z * ad[j*4+2] + w.w * ad[j*4+3];
  }
  s_src[t] = ss;
  s_dst[t] = sd;
}

// ---------------- K4: per-edge logits + dst histogram
__global__ __launch_bounds__(256) void edge_kernel(
    const float* __restrict__ edge_feats, const int* __restrict__ src,
    const int* __restrict__ dst, const float* __restrict__ Wfold,
    const float* __restrict__ bfold, const float* __restrict__ s_src,
    const float* __restrict__ s_dst, float* __restrict__ elog,
    int* __restrict__ deg) {
  int e = blockIdx.x * blockDim.x + threadIdx.x;   // exact 640000
  float acc[8];
  #pragma unroll
  for (int h = 0; h < 8; h++) acc[h] = bfold[h];
  const float4* ef4 = (const float4*)(edge_feats + (size_t)e * EDGE_FEATS);
  #pragma unroll
  for (int k4 = 0; k4 < 16; k4++) {
    float4 f = ef4[k4];
    #pragma unroll
    for (int h = 0; h < 8; h++) {
      const float* wr = Wfold + h * EDGE_FEATS + k4 * 4;  // uniform -> s_load
      acc[h] += f.x * wr[0] + f.y * wr[1] + f.z * wr[2] + f.w * wr[3];
    }
  }
  int s = src[e], d = dst[e];
  const float4* ss4 = (const float4*)(s_src + (size_t)s * 8);
  const float4* sd4 = (const float4*)(s_dst + (size_t)d * 8);
  float4 sa = ss4[0], sb = ss4[1];
  float4 da = sd4[0], db = sd4[1];
  float v[8];
  v[0] = acc[0] + sa.x + da.x; v[1] = acc[1] + sa.y + da.y;
  v[2] = acc[2] + sa.z + da.z; v[3] = acc[3] + sa.w + da.w;
  v[4] = acc[4] + sb.x + db.x; v[5] = acc[5] + sb.y + db.y;
  v[6] = acc[6] + sb.z + db.z; v[7] = acc[7] + sb.w + db.w;
  #pragma unroll
  for (int h = 0; h < 8; h++) v[h] = v[h] > 0.f ? v[h] : 0.2f * v[h];
  float4* eo = (float4*)(elog + (size_t)e * 8);
  eo[0] = make_float4(v[0], v[1], v[2], v[3]);
  eo[1] = make_float4(v[4], v[5], v[6], v[7]);
  atomicAdd(&deg[d], 1);
}

// ---------------- K5: single-block exclusive scan of deg -> rs, cursor
__global__ __launch_bounds__(1024) void scan_kernel(
    const int* __restrict__ deg, int* __restrict__ rs, int* __restrict__ cursor) {
  __shared__ int wsum[16];
  __shared__ int carry_s;
  int tid = threadIdx.x;
  int lane = tid & 63, w = tid >> 6;
  if (tid == 0) carry_s = 0;
  __syncthreads();
  for (int chunk = 0; chunk < 40; chunk++) {   // 40 * 1024 >= 40000
    int i = chunk * 1024 + tid;
    int v = (i < N_NODES) ? deg[i] : 0;
    int x = v;
    #pragma unroll
    for (int off = 1; off < 64; off <<= 1) {
      int y = __shfl_up(x, off, 64);
      if (lane >= off) x += y;
    }
    if (lane == 63) wsum[w] = x;
    __syncthreads();
    int wadd = 0;
    for (int j = 0; j < w; j++) wadd += wsum[j];
    int incl = x + wadd;
    int excl = incl - v + carry_s;
    if (i < N_NODES) { rs[i] = excl; cursor[i] = excl; }
    __syncthreads();
    if (tid == 1023) carry_s += incl;
    __syncthreads();
  }
  if (tid == 0) rs[N_NODES] = carry_s;
}

// ---------------- K6: scatter edge ids into CSR
__global__ __launch_bounds__(256) void scatter_kernel(
    const int* __restrict__ dst, int* __restrict__ cursor, int* __restrict__ csr) {
  int e = blockIdx.x * blockDim.x + threadIdx.x;   // exact 640000
  int d = dst[e];
  int pos = atomicAdd(&cursor[d], 1);
  csr[pos] = e;
}

// ---------------- K7: per-node softmax + aggregation (1 wave / node)
__global__ __launch_bounds__(256) void aggregate_kernel(
    const int* __restrict__ rs, const int* __restrict__ csr,
    const int* __restrict__ src, const float* __restrict__ elog,
    const float* __restrict__ Wh, float* __restrict__ out) {
  int node = blockIdx.x * 4 + (threadIdx.x >> 6);
  int lane = threadIdx.x & 63;
  int h1 = lane >> 4;       // head for output element o1 = lane
  int h2 = h1 + 4;          // head for output element o2 = lane + 64
  int start = rs[node], end = rs[node + 1];

  float m1 = -1e30f, m2 = -1e30f;
  for (int i = start; i < end; i++) {
    int e = csr[i];
    m1 = fmaxf(m1, elog[e * 8 + h1]);
    m2 = fmaxf(m2, elog[e * 8 + h2]);
  }
  float z1 = 0.f, z2 = 0.f, a1 = 0.f, a2 = 0.f;
  for (int i = start; i < end; i++) {
    int e = csr[i];
    int s = src[e];
    float ex1 = __expf(elog[e * 8 + h1] - m1);
    float ex2 = __expf(elog[e * 8 + h2] - m2);
    z1 += ex1; z2 += ex2;
    a1 += ex1 * Wh[s * OUT_FEATS + lane];
    a2 += ex2 * Wh[s * OUT_FEATS + 64 + lane];
  }
  float o1 = (end > start) ? a1 / z1 : 0.f;
  float o2 = (end > start) ? a2 / z2 : 0.f;
  out[(size_t)node * OUT_FEATS + lane] = o1;
  out[(size_t)node * OUT_FEATS + 64 + lane] = o2;
}

extern "C" void kernel_launch(void* const* d_in, const int* in_sizes, int n_in,
                              void* d_out, int out_size, void* d_ws, size_t ws_size,
                              hipStream_t stream) {
  const float* node_feats = (const float*)d_in[0];
  const float* edge_feats = (const float*)d_in[1];
  const int*   src        = (const int*)d_in[2];
  const int*   dst        = (const int*)d_in[3];
  const float* node_w     = (const float*)d_in[4];
  const float* node_b     = (const float*)d_in[5];
  const float* edge_w     = (const float*)d_in[6];
  const float* edge_b     = (const float*)d_in[7];
  const float* attn       = (const float*)d_in[8];
  float* out = (float*)d_out;

  char* ws = (char*)d_ws;
  size_t off = 0;
  auto alloc = [&](size_t bytes) {
    void* p = ws + off;
    off += (bytes + 255) & ~(size_t)255;
    return p;
  };
  float* Wh     = (float*)alloc((size_t)N_NODES * OUT_FEATS * 4);   // 20.48 MB
  float* s_src  = (float*)alloc((size_t)N_NODES * NUM_HEADS * 4);   // 1.28 MB
  float* s_dst  = (float*)alloc((size_t)N_NODES * NUM_HEADS * 4);   // 1.28 MB
  float* elog   = (float*)alloc((size_t)N_EDGES * NUM_HEADS * 4);   // 20.48 MB
  int*   csr    = (int*)alloc((size_t)N_EDGES * 4);                 // 2.56 MB
  int*   deg    = (int*)alloc((size_t)N_NODES * 4);
  int*   rs     = (int*)alloc((size_t)(N_NODES + 1) * 4);
  int*   cursor = (int*)alloc((size_t)N_NODES * 4);
  float* Wfold  = (float*)alloc(NUM_HEADS * EDGE_FEATS * 4);
  float* bfold  = (float*)alloc(NUM_HEADS * 4);

  hipMemsetAsync(deg, 0, (size_t)N_NODES * 4, stream);

  fold_kernel<<<1, 512, 0, stream>>>(edge_w, edge_b, attn, Wfold, bfold);
  wh_gemm<<<(N_NODES / 16 + 3) / 4, 256, 0, stream>>>(node_feats, node_w, node_b, Wh);
  ssd_kernel<<<(N_NODES * NUM_HEADS + 255) / 256, 256, 0, stream>>>(Wh, attn, s_src, s_dst);
  edge_kernel<<<N_EDGES / 256, 256, 0, stream>>>(edge_feats, src, dst, Wfold, bfold,
                                                 s_src, s_dst, elog, deg);
  scan_kernel<<<1, 1024, 0, stream>>>(deg, rs, cursor);
  scatter_kernel<<<N_EDGES / 256, 256, 0, stream>>>(dst, cursor, csr);
  aggregate_kernel<<<N_NODES / 4, 256, 0, stream>>>(rs, csr, src, elog, Wh, out);
}

// Round 2
// 557.447 us; speedup vs baseline: 1.0616x; 1.0616x over previous
//
#include <hip/hip_runtime.h>
#include <stdint.h>
#include <stddef.h>

#define N_NODES   40000
#define N_EDGES   640000
#define IN_FEATS  256
#define EDGE_FEATS 64
#define OUT_FEATS 128
#define NUM_HEADS 8
#define HD        16   // per-head dim

typedef __attribute__((ext_vector_type(8))) short  short8;   // 8 x bf16 bits
typedef __attribute__((ext_vector_type(4))) float  floatx4;

__device__ inline short f2bf(float f) {
  union { float f; uint32_t u; } v; v.f = f;
  uint32_t r = v.u + 0x7fffu + ((v.u >> 16) & 1u);   // RNE
  return (short)(r >> 16);
}

__device__ inline short8 cvt8(float4 lo, float4 hi) {
  short8 r;
  r[0] = f2bf(lo.x); r[1] = f2bf(lo.y); r[2] = f2bf(lo.z); r[3] = f2bf(lo.w);
  r[4] = f2bf(hi.x); r[5] = f2bf(hi.y); r[6] = f2bf(hi.z); r[7] = f2bf(hi.w);
  return r;
}

__device__ inline float bflo(uint32_t w) {
  union { uint32_t u; float f; } v; v.u = w << 16; return v.f;
}
__device__ inline float bfhi(uint32_t w) {
  union { uint32_t u; float f; } v; v.u = w & 0xffff0000u; return v.f;
}

// ---------------- K-hist: dst histogram
__global__ __launch_bounds__(256) void hist_kernel(
    const int* __restrict__ dst, int* __restrict__ deg) {
  int e = blockIdx.x * 256 + threadIdx.x;   // exact 640000
  atomicAdd(&deg[dst[e]], 1);
}

// ---------------- K-gemm: Whp (packed bf16) = node_feats @ node_w^T + node_b
// one wave computes a 16(M) x 128(N) strip; K=256 in 8 steps of 32
// Whp[m][w] dword: low bf16 = Wh[m][w], high bf16 = Wh[m][w+64], w in [0,64)
__global__ __launch_bounds__(256) void wh_gemm(
    const float* __restrict__ A,     // node_feats [40000][256]
    const float* __restrict__ W,     // node_w [128][256] (K-major, = B^T)
    const float* __restrict__ bias,  // node_b [128]
    uint32_t* __restrict__ Whp) {    // [40000][64] packed
  int wave = (blockIdx.x * blockDim.x + threadIdx.x) >> 6;
  int lane = threadIdx.x & 63;
  int m0 = wave * 16;
  if (m0 >= N_NODES) return;
  int row = lane & 15, quad = lane >> 4;

  floatx4 acc[8];
  #pragma unroll
  for (int nt = 0; nt < 8; nt++) acc[nt] = (floatx4)(0.f);

  const float4* A4 = (const float4*)A;
  const float4* W4 = (const float4*)W;
  int a_base = ((m0 + row) * IN_FEATS + quad * 8) >> 2;   // in float4 units

  #pragma unroll
  for (int s = 0; s < 8; s++) {
    float4 alo = A4[a_base + s * 8];
    float4 ahi = A4[a_base + s * 8 + 1];
    short8 af = cvt8(alo, ahi);
    #pragma unroll
    for (int nt = 0; nt < 8; nt++) {
      int b_base = ((nt * 16 + row) * IN_FEATS + s * 32 + quad * 8) >> 2;
      float4 blo = W4[b_base];
      float4 bhi = W4[b_base + 1];
      short8 bf = cvt8(blo, bhi);
      acc[nt] = __builtin_amdgcn_mfma_f32_16x16x32_bf16(af, bf, acc[nt], 0, 0, 0);
    }
  }
  // C/D layout: n = nt*16 + row, m = m0 + quad*4 + r
  #pragma unroll
  for (int nt = 0; nt < 4; nt++) {
    float blo_ = bias[nt * 16 + row];
    float bhi_ = bias[64 + nt * 16 + row];
    #pragma unroll
    for (int r = 0; r < 4; r++) {
      int m = m0 + quad * 4 + r;
      float lo = acc[nt][r] + blo_;
      float hi = acc[nt + 4][r] + bhi_;
      uint32_t d = (uint32_t)(uint16_t)f2bf(lo) |
                   ((uint32_t)(uint16_t)f2bf(hi) << 16);
      Whp[m * 64 + nt * 16 + row] = d;
    }
  }
}

// ---------------- K-ssd: s_src[n][h], s_dst[n][h] from packed Whp
__global__ __launch_bounds__(256) void ssd_kernel(
    const uint32_t* __restrict__ Whp, const float* __restrict__ attn,
    float* __restrict__ s_src, float* __restrict__ s_dst) {
  int t = blockIdx.x * 256 + threadIdx.x;   // exact 160000 = 40000*4
  int n = t >> 2, hp = t & 3;               // hp = head pair (hp, hp+4)
  const uint4* p = (const uint4*)(Whp + n * 64 + hp * 16);
  const float* as_lo = attn + hp * 48;
  const float* ad_lo = attn + hp * 48 + 16;
  const float* as_hi = attn + (hp + 4) * 48;
  const float* ad_hi = attn + (hp + 4) * 48 + 16;
  float ss_lo = 0.f, sd_lo = 0.f, ss_hi = 0.f, sd_hi = 0.f;
  #pragma unroll
  for (int q = 0; q < 4; q++) {
    uint4 u = p[q];
    uint32_t ws[4] = {u.x, u.y, u.z, u.w};
    #pragma unroll
    for (int k = 0; k < 4; k++) {
      int d = q * 4 + k;
      float lo = bflo(ws[k]), hi = bfhi(ws[k]);
      ss_lo += lo * as_lo[d]; sd_lo += lo * ad_lo[d];
      ss_hi += hi * as_hi[d]; sd_hi += hi * ad_hi[d];
    }
  }
  s_src[n * 8 + hp]     = ss_lo;
  s_src[n * 8 + hp + 4] = ss_hi;
  s_dst[n * 8 + hp]     = sd_lo;
  s_dst[n * 8 + hp + 4] = sd_hi;
}

// ---------------- K-foldscan: fold edge_w/b with a_e; exclusive scan of deg
__global__ __launch_bounds__(1024) void foldscan_kernel(
    const float* __restrict__ edge_w, const float* __restrict__ edge_b,
    const float* __restrict__ attn, float* __restrict__ Wfold,
    float* __restrict__ bfold, const int* __restrict__ deg,
    int* __restrict__ rs, int* __restrict__ cursor) {
  int tid = threadIdx.x;
  // --- fold (threads 0..511), independent of scan ---
  if (tid < 512) {
    int h = tid >> 6, k = tid & 63;
    float s = 0.f;
    #pragma unroll
    for (int d = 0; d < HD; d++)
      s += edge_w[(h * HD + d) * EDGE_FEATS + k] * attn[h * 48 + 32 + d];
    Wfold[h * EDGE_FEATS + k] = s;
    if (k == 0) {
      float b = 0.f;
      #pragma unroll
      for (int d = 0; d < HD; d++)
        b += edge_b[h * HD + d] * attn[h * 48 + 32 + d];
      bfold[h] = b;
    }
  }
  // --- scan: thread t owns deg[t*40 .. t*40+40) ---
  __shared__ int wsum[16];
  const int PER = 40;                      // 1024*40 = 40960 >= 40000
  int lane = tid & 63, w = tid >> 6;
  int base = tid * PER;
  int s = 0;
  for (int j = 0; j < PER; j++) {
    int i = base + j;
    if (i < N_NODES) s += deg[i];
  }
  int x = s;
  #pragma unroll
  for (int off = 1; off < 64; off <<= 1) {
    int y = __shfl_up(x, off, 64);
    if (lane >= off) x += y;
  }
  if (lane == 63) wsum[w] = x;
  __syncthreads();
  int prefix = 0, total = 0;
  for (int j = 0; j < 16; j++) {
    int v = wsum[j];
    if (j < w) prefix += v;
    total += v;
  }
  int run = prefix + x - s;                // exclusive prefix for this chunk
  for (int j = 0; j < PER; j++) {
    int i = base + j;
    if (i < N_NODES) {
      int v = deg[i];
      rs[i] = run; cursor[i] = run;
      run += v;
    }
  }
  if (tid == 0) rs[N_NODES] = total;
}

// ---------------- K-edge: per-edge logits, written in CSR (dst-grouped) order
__global__ __launch_bounds__(256) void edge_kernel(
    const float* __restrict__ edge_feats, const int* __restrict__ src,
    const int* __restrict__ dst, const float* __restrict__ Wfold,
    const float* __restrict__ bfold, const float* __restrict__ s_src,
    const float* __restrict__ s_dst, int* __restrict__ cursor,
    int* __restrict__ perm_src, float* __restrict__ perm_elog) {
  int e = blockIdx.x * 256 + threadIdx.x;   // exact 640000
  float acc[8];
  #pragma unroll
  for (int h = 0; h < 8; h++) acc[h] = bfold[h];
  const float4* ef4 = (const float4*)(edge_feats + (size_t)e * EDGE_FEATS);
  #pragma unroll
  for (int k4 = 0; k4 < 16; k4++) {
    float4 f = ef4[k4];
    #pragma unroll
    for (int h = 0; h < 8; h++) {
      const float* wr = Wfold + h * EDGE_FEATS + k4 * 4;  // wave-uniform
      acc[h] += f.x * wr[0] + f.y * wr[1] + f.z * wr[2] + f.w * wr[3];
    }
  }
  int s = src[e], d = dst[e];
  const float4* ss4 = (const float4*)(s_src + (size_t)s * 8);
  const float4* sd4 = (const float4*)(s_dst + (size_t)d * 8);
  float4 sa = ss4[0], sb = ss4[1];
  float4 da = sd4[0], db = sd4[1];
  float v[8];
  v[0] = acc[0] + sa.x + da.x; v[1] = acc[1] + sa.y + da.y;
  v[2] = acc[2] + sa.z + da.z; v[3] = acc[3] + sa.w + da.w;
  v[4] = acc[4] + sb.x + db.x; v[5] = acc[5] + sb.y + db.y;
  v[6] = acc[6] + sb.z + db.z; v[7] = acc[7] + sb.w + db.w;
  #pragma unroll
  for (int h = 0; h < 8; h++) v[h] = v[h] > 0.f ? v[h] : 0.2f * v[h];
  int pos = atomicAdd(&cursor[d], 1);
  perm_src[pos] = s;
  float4* eo = (float4*)(perm_elog + (size_t)pos * 8);
  eo[0] = make_float4(v[0], v[1], v[2], v[3]);
  eo[1] = make_float4(v[4], v[5], v[6], v[7]);
}

// ---------------- K-agg: per-node one-pass online softmax + aggregation
// 1 wave / node; lane covers output features (lane, lane+64)
__global__ __launch_bounds__(256) void aggregate_kernel(
    const int* __restrict__ rs, const int* __restrict__ perm_src,
    const float* __restrict__ perm_elog, const uint32_t* __restrict__ Whp,
    float* __restrict__ out) {
  int node = blockIdx.x * 4 + (threadIdx.x >> 6);
  int lane = threadIdx.x & 63;
  int h1 = lane >> 4;       // head of feature `lane`
  int h2 = h1 + 4;          // head of feature `lane+64`
  int start = rs[node], end = rs[node + 1];

  float m1 = -1e30f, m2 = -1e30f;
  float z1 = 0.f, z2 = 0.f, a1 = 0.f, a2 = 0.f;
  for (int i = start; i < end; i++) {
    int s = perm_src[i];
    float l1 = perm_elog[(size_t)i * 8 + h1];
    float l2 = perm_elog[(size_t)i * 8 + h2];
    uint32_t w = Whp[(size_t)s * 64 + lane];   // coalesced 256B row gather
    float wlo = bflo(w), whi = bfhi(w);
    float nm1 = fmaxf(m1, l1);
    float nm2 = fmaxf(m2, l2);
    float sc1 = __expf(m1 - nm1);
    float sc2 = __expf(m2 - nm2);
    float ex1 = __expf(l1 - nm1);
    float ex2 = __expf(l2 - nm2);
    z1 = z1 * sc1 + ex1;
    z2 = z2 * sc2 + ex2;
    a1 = a1 * sc1 + ex1 * wlo;
    a2 = a2 * sc2 + ex2 * whi;
    m1 = nm1; m2 = nm2;
  }
  float o1 = (end > start) ? a1 / z1 : 0.f;
  float o2 = (end > start) ? a2 / z2 : 0.f;
  out[(size_t)node * OUT_FEATS + lane] = o1;
  out[(size_t)node * OUT_FEATS + 64 + lane] = o2;
}

extern "C" void kernel_launch(void* const* d_in, const int* in_sizes, int n_in,
                              void* d_out, int out_size, void* d_ws, size_t ws_size,
                              hipStream_t stream) {
  const float* node_feats = (const float*)d_in[0];
  const float* edge_feats = (const float*)d_in[1];
  const int*   src        = (const int*)d_in[2];
  const int*   dst        = (const int*)d_in[3];
  const float* node_w     = (const float*)d_in[4];
  const float* node_b     = (const float*)d_in[5];
  const float* edge_w     = (const float*)d_in[6];
  const float* edge_b     = (const float*)d_in[7];
  const float* attn       = (const float*)d_in[8];
  float* out = (float*)d_out;

  char* ws = (char*)d_ws;
  size_t off = 0;
  auto alloc = [&](size_t bytes) {
    void* p = ws + off;
    off += (bytes + 255) & ~(size_t)255;
    return p;
  };
  uint32_t* Whp      = (uint32_t*)alloc((size_t)N_NODES * 64 * 4);      // 10.24 MB
  float*    s_src    = (float*)alloc((size_t)N_NODES * NUM_HEADS * 4);  // 1.28 MB
  float*    s_dst    = (float*)alloc((size_t)N_NODES * NUM_HEADS * 4);  // 1.28 MB
  float*    perm_elog= (float*)alloc((size_t)N_EDGES * NUM_HEADS * 4);  // 20.48 MB
  int*      perm_src = (int*)alloc((size_t)N_EDGES * 4);                // 2.56 MB
  int*      deg      = (int*)alloc((size_t)N_NODES * 4);
  int*      rs       = (int*)alloc((size_t)(N_NODES + 1) * 4);
  int*      cursor   = (int*)alloc((size_t)N_NODES * 4);
  float*    Wfold    = (float*)alloc(NUM_HEADS * EDGE_FEATS * 4);
  float*    bfold    = (float*)alloc(NUM_HEADS * 4);

  hipMemsetAsync(deg, 0, (size_t)N_NODES * 4, stream);

  hist_kernel<<<N_EDGES / 256, 256, 0, stream>>>(dst, deg);
  wh_gemm<<<N_NODES / 16 / 4, 256, 0, stream>>>(node_feats, node_w, node_b, Whp);
  ssd_kernel<<<N_NODES * 4 / 256, 256, 0, stream>>>(Whp, attn, s_src, s_dst);
  foldscan_kernel<<<1, 1024, 0, stream>>>(edge_w, edge_b, attn, Wfold, bfold,
                                          deg, rs, cursor);
  edge_kernel<<<N_EDGES / 256, 256, 0, stream>>>(edge_feats, src, dst, Wfold,
                                                 bfold, s_src, s_dst, cursor,
                                                 perm_src, perm_elog);
  aggregate_kernel<<<N_NODES / 4, 256, 0, stream>>>(rs, perm_src, perm_elog,
                                                    Whp, out);
}

// Round 3
// 509.621 us; speedup vs baseline: 1.1612x; 1.0938x over previous
//
#include <hip/hip_runtime.h>
#include <hip/hip_fp16.h>
#include <stdint.h>
#include <stddef.h>

#define N_NODES   40000
#define N_EDGES   640000
#define IN_FEATS  256
#define EDGE_FEATS 64
#define OUT_FEATS 128
#define NUM_HEADS 8
#define HD        16   // per-head dim

typedef __attribute__((ext_vector_type(8))) short  short8;   // 8 x bf16 bits
typedef __attribute__((ext_vector_type(4))) float  floatx4;

__device__ inline short f2bf(float f) {
  union { float f; uint32_t u; } v; v.f = f;
  uint32_t r = v.u + 0x7fffu + ((v.u >> 16) & 1u);   // RNE
  return (short)(r >> 16);
}

__device__ inline short8 cvt8(float4 lo, float4 hi) {
  short8 r;
  r[0] = f2bf(lo.x); r[1] = f2bf(lo.y); r[2] = f2bf(lo.z); r[3] = f2bf(lo.w);
  r[4] = f2bf(hi.x); r[5] = f2bf(hi.y); r[6] = f2bf(hi.z); r[7] = f2bf(hi.w);
  return r;
}

__device__ inline float bflo(uint32_t w) {
  union { uint32_t u; float f; } v; v.u = w << 16; return v.f;
}
__device__ inline float bfhi(uint32_t w) {
  union { uint32_t u; float f; } v; v.u = w & 0xffff0000u; return v.f;
}

// ---------------- K1: prep (block 0: fold + W->bf16) + dst histogram
__global__ __launch_bounds__(512) void prep_hist_kernel(
    const float* __restrict__ edge_w, const float* __restrict__ edge_b,
    const float* __restrict__ attn, const float* __restrict__ node_w,
    const int* __restrict__ dst,
    float* __restrict__ Wfold, float* __restrict__ bfold,
    uint32_t* __restrict__ Wbf, int* __restrict__ deg) {
  int tid = threadIdx.x;
  if (blockIdx.x == 0) {
    // fold edge_w/edge_b with a_e -> Wfold[8][64], bfold[8]
    int h = tid >> 6, k = tid & 63;
    float s = 0.f;
    #pragma unroll
    for (int d = 0; d < HD; d++)
      s += edge_w[(h * HD + d) * EDGE_FEATS + k] * attn[h * 48 + 32 + d];
    Wfold[h * EDGE_FEATS + k] = s;
    if (k == 0) {
      float b = 0.f;
      #pragma unroll
      for (int d = 0; d < HD; d++)
        b += edge_b[h * HD + d] * attn[h * 48 + 32 + d];
      bfold[h] = b;
    }
    // convert node_w (128x256 fp32) -> packed bf16 (16384 dwords)
    const float2* W2 = (const float2*)node_w;
    #pragma unroll
    for (int j = 0; j < 32; j++) {
      int p = j * 512 + tid;
      float2 f = W2[p];
      Wbf[p] = (uint32_t)(uint16_t)f2bf(f.x) |
               ((uint32_t)(uint16_t)f2bf(f.y) << 16);
    }
  } else {
    int e = (blockIdx.x - 1) * 512 + tid;   // 1250 blocks * 512 = 640000
    atomicAdd(&deg[dst[e]], 1);
  }
}

// ---------------- K2: Whp (packed bf16) = node_feats @ node_w^T + node_b
// one wave computes a 16(M) x 128(N) strip; K=256 in 8 steps of 32
// Whp[m][w] dword: low bf16 = Wh[m][w], high bf16 = Wh[m][w+64], w in [0,64)
__global__ __launch_bounds__(256) void wh_gemm(
    const float* __restrict__ A,       // node_feats [40000][256]
    const uint32_t* __restrict__ Wbf,  // node_w bf16-packed [128][256]
    const float* __restrict__ bias,    // node_b [128]
    uint32_t* __restrict__ Whp) {      // [40000][64] packed
  int wave = (blockIdx.x * blockDim.x + threadIdx.x) >> 6;
  int lane = threadIdx.x & 63;
  int m0 = wave * 16;
  if (m0 >= N_NODES) return;
  int row = lane & 15, quad = lane >> 4;

  floatx4 acc[8];
  #pragma unroll
  for (int nt = 0; nt < 8; nt++) acc[nt] = (floatx4)(0.f);

  const float4* A4 = (const float4*)A;
  const uint4*  W4 = (const uint4*)Wbf;
  int a_base = ((m0 + row) * IN_FEATS + quad * 8) >> 2;   // float4 units

  #pragma unroll
  for (int s = 0; s < 8; s++) {
    float4 alo = A4[a_base + s * 8];
    float4 ahi = A4[a_base + s * 8 + 1];
    short8 af = cvt8(alo, ahi);
    #pragma unroll
    for (int nt = 0; nt < 8; nt++) {
      int fo = (nt * 16 + row) * IN_FEATS + s * 32 + quad * 8;
      uint4 u = W4[fo >> 3];
      short8 bf = *(short8*)&u;
      acc[nt] = __builtin_amdgcn_mfma_f32_16x16x32_bf16(af, bf, acc[nt], 0, 0, 0);
    }
  }
  // C/D layout: n = nt*16 + row, m = m0 + quad*4 + r
  #pragma unroll
  for (int nt = 0; nt < 4; nt++) {
    float blo_ = bias[nt * 16 + row];
    float bhi_ = bias[64 + nt * 16 + row];
    #pragma unroll
    for (int r = 0; r < 4; r++) {
      int m = m0 + quad * 4 + r;
      float lo = acc[nt][r] + blo_;
      float hi = acc[nt + 4][r] + bhi_;
      uint32_t d = (uint32_t)(uint16_t)f2bf(lo) |
                   ((uint32_t)(uint16_t)f2bf(hi) << 16);
      Whp[m * 64 + nt * 16 + row] = d;
    }
  }
}

// ---------------- K3: s_src[n][h], s_dst[n][h] from packed Whp
__global__ __launch_bounds__(256) void ssd_kernel(
    const uint32_t* __restrict__ Whp, const float* __restrict__ attn,
    float* __restrict__ s_src, float* __restrict__ s_dst) {
  int t = blockIdx.x * 256 + threadIdx.x;   // exact 160000 = 40000*4
  int n = t >> 2, hp = t & 3;               // head pair (hp, hp+4)
  const uint4* p = (const uint4*)(Whp + n * 64 + hp * 16);
  const float* as_lo = attn + hp * 48;
  const float* ad_lo = attn + hp * 48 + 16;
  const float* as_hi = attn + (hp + 4) * 48;
  const float* ad_hi = attn + (hp + 4) * 48 + 16;
  float ss_lo = 0.f, sd_lo = 0.f, ss_hi = 0.f, sd_hi = 0.f;
  #pragma unroll
  for (int q = 0; q < 4; q++) {
    uint4 u = p[q];
    uint32_t ws[4] = {u.x, u.y, u.z, u.w};
    #pragma unroll
    for (int k = 0; k < 4; k++) {
      int d = q * 4 + k;
      float lo = bflo(ws[k]), hi = bfhi(ws[k]);
      ss_lo += lo * as_lo[d]; sd_lo += lo * ad_lo[d];
      ss_hi += hi * as_hi[d]; sd_hi += hi * ad_hi[d];
    }
  }
  s_src[n * 8 + hp]     = ss_lo;
  s_src[n * 8 + hp + 4] = ss_hi;
  s_dst[n * 8 + hp]     = sd_lo;
  s_dst[n * 8 + hp + 4] = sd_hi;
}

// ---------------- K4: exclusive scan of deg -> rs, cursor (single block)
__global__ __launch_bounds__(1024) void scan_kernel(
    const int* __restrict__ deg, int* __restrict__ rs, int* __restrict__ cursor) {
  __shared__ int wsum[16];
  const int PER = 40;                      // 1024*40 = 40960 >= 40000
  int tid = threadIdx.x;
  int lane = tid & 63, w = tid >> 6;
  int base = tid * PER;
  int s = 0;
  for (int j = 0; j < PER; j++) {
    int i = base + j;
    if (i < N_NODES) s += deg[i];
  }
  int x = s;
  #pragma unroll
  for (int off = 1; off < 64; off <<= 1) {
    int y = __shfl_up(x, off, 64);
    if (lane >= off) x += y;
  }
  if (lane == 63) wsum[w] = x;
  __syncthreads();
  int prefix = 0, total = 0;
  for (int j = 0; j < 16; j++) {
    int v = wsum[j];
    if (j < w) prefix += v;
    total += v;
  }
  int run = prefix + x - s;                // exclusive prefix for this chunk
  for (int j = 0; j < PER; j++) {
    int i = base + j;
    if (i < N_NODES) {
      int v = deg[i];
      rs[i] = run; cursor[i] = run;
      run += v;
    }
  }
  if (tid == 0) rs[N_NODES] = total;
}

// ---------------- K5: per-edge logits, scattered in CSR (dst-grouped) order
// record: perm_src[pos] (int) + perm_lg[pos] (uint4 = 8 x fp16, head-order)
__global__ __launch_bounds__(256) void edge_kernel(
    const float* __restrict__ edge_feats, const int* __restrict__ src,
    const int* __restrict__ dst, const float* __restrict__ Wfold,
    const float* __restrict__ bfold, const float* __restrict__ s_src,
    const float* __restrict__ s_dst, int* __restrict__ cursor,
    int* __restrict__ perm_src, uint4* __restrict__ perm_lg) {
  int e = blockIdx.x * 256 + threadIdx.x;   // exact 640000
  // issue index + gather loads first so latency overlaps the dot loop
  int s = src[e], d = dst[e];
  const float4* ss4 = (const float4*)(s_src + (size_t)s * 8);
  const float4* sd4 = (const float4*)(s_dst + (size_t)d * 8);
  float4 sa = ss4[0], sb = ss4[1];
  float4 da = sd4[0], db = sd4[1];
  int pos = atomicAdd(&cursor[d], 1);

  float acc[8];
  #pragma unroll
  for (int h = 0; h < 8; h++) acc[h] = bfold[h];
  const float4* ef4 = (const float4*)(edge_feats + (size_t)e * EDGE_FEATS);
  #pragma unroll
  for (int k4 = 0; k4 < 16; k4++) {
    float4 f = ef4[k4];
    #pragma unroll
    for (int h = 0; h < 8; h++) {
      const float* wr = Wfold + h * EDGE_FEATS + k4 * 4;  // wave-uniform
      acc[h] += f.x * wr[0] + f.y * wr[1] + f.z * wr[2] + f.w * wr[3];
    }
  }
  float v[8];
  v[0] = acc[0] + sa.x + da.x; v[1] = acc[1] + sa.y + da.y;
  v[2] = acc[2] + sa.z + da.z; v[3] = acc[3] + sa.w + da.w;
  v[4] = acc[4] + sb.x + db.x; v[5] = acc[5] + sb.y + db.y;
  v[6] = acc[6] + sb.z + db.z; v[7] = acc[7] + sb.w + db.w;
  #pragma unroll
  for (int h = 0; h < 8; h++) v[h] = v[h] > 0.f ? v[h] : 0.2f * v[h];

  uint32_t pk[4];
  #pragma unroll
  for (int j = 0; j < 4; j++) {
    uint32_t lo = __half_as_ushort(__float2half_rn(v[2 * j]));
    uint32_t hi = __half_as_ushort(__float2half_rn(v[2 * j + 1]));
    pk[j] = lo | (hi << 16);
  }
  perm_src[pos] = s;
  perm_lg[pos] = make_uint4(pk[0], pk[1], pk[2], pk[3]);
}

// ---------------- K6: per-node softmax (no-max exp) + aggregation
// 1 wave / node; lane covers output features (lane, lane+64)
__global__ __launch_bounds__(256) void aggregate_kernel(
    const int* __restrict__ rs, const int* __restrict__ perm_src,
    const uint4* __restrict__ perm_lg, const uint32_t* __restrict__ Whp,
    float* __restrict__ out) {
  int node = blockIdx.x * 4 + (threadIdx.x >> 6);
  int lane = threadIdx.x & 63;
  int h1 = lane >> 4;       // head of feature `lane` (0..3)
  int start = rs[node], end = rs[node + 1];
  uint32_t sh = (h1 & 1) * 16;
  bool hi_pair = (h1 & 2) != 0;

  float z1 = 0.f, z2 = 0.f, a1 = 0.f, a2 = 0.f;
  int i = start;
  for (; i + 1 < end; i += 2) {
    int s0 = perm_src[i], s1 = perm_src[i + 1];
    uint4 lgA = perm_lg[i];
    uint4 lgB = perm_lg[i + 1];
    uint32_t wA = Whp[(size_t)s0 * 64 + lane];
    uint32_t wB = Whp[(size_t)s1 * 64 + lane];
    uint32_t c1A = hi_pair ? lgA.y : lgA.x;
    uint32_t c2A = hi_pair ? lgA.w : lgA.z;
    uint32_t c1B = hi_pair ? lgB.y : lgB.x;
    uint32_t c2B = hi_pair ? lgB.w : lgB.z;
    float l1A = __half2float(__ushort_as_half((uint16_t)(c1A >> sh)));
    float l2A = __half2float(__ushort_as_half((uint16_t)(c2A >> sh)));
    float l1B = __half2float(__ushort_as_half((uint16_t)(c1B >> sh)));
    float l2B = __half2float(__ushort_as_half((uint16_t)(c2B >> sh)));
    float e1A = __expf(l1A), e2A = __expf(l2A);
    float e1B = __expf(l1B), e2B = __expf(l2B);
    z1 += e1A + e1B; z2 += e2A + e2B;
    a1 += e1A * bflo(wA) + e1B * bflo(wB);
    a2 += e2A * bfhi(wA) + e2B * bfhi(wB);
  }
  if (i < end) {
    int s0 = perm_src[i];
    uint4 lgA = perm_lg[i];
    uint32_t wA = Whp[(size_t)s0 * 64 + lane];
    uint32_t c1A = hi_pair ? lgA.y : lgA.x;
    uint32_t c2A = hi_pair ? lgA.w : lgA.z;
    float l1A = __half2float(__ushort_as_half((uint16_t)(c1A >> sh)));
    float l2A = __half2float(__ushort_as_half((uint16_t)(c2A >> sh)));
    float e1A = __expf(l1A), e2A = __expf(l2A);
    z1 += e1A; z2 += e2A;
    a1 += e1A * bflo(wA);
    a2 += e2A * bfhi(wA);
  }
  float o1 = (end > start) ? a1 / z1 : 0.f;
  float o2 = (end > start) ? a2 / z2 : 0.f;
  out[(size_t)node * OUT_FEATS + lane] = o1;
  out[(size_t)node * OUT_FEATS + 64 + lane] = o2;
}

extern "C" void kernel_launch(void* const* d_in, const int* in_sizes, int n_in,
                              void* d_out, int out_size, void* d_ws, size_t ws_size,
                              hipStream_t stream) {
  const float* node_feats = (const float*)d_in[0];
  const float* edge_feats = (const float*)d_in[1];
  const int*   src        = (const int*)d_in[2];
  const int*   dst        = (const int*)d_in[3];
  const float* node_w     = (const float*)d_in[4];
  const float* node_b     = (const float*)d_in[5];
  const float* edge_w     = (const float*)d_in[6];
  const float* edge_b     = (const float*)d_in[7];
  const float* attn       = (const float*)d_in[8];
  float* out = (float*)d_out;

  char* ws = (char*)d_ws;
  size_t off = 0;
  auto alloc = [&](size_t bytes) {
    void* p = ws + off;
    off += (bytes + 255) & ~(size_t)255;
    return p;
  };
  uint32_t* Whp      = (uint32_t*)alloc((size_t)N_NODES * 64 * 4);      // 10.24 MB
  float*    s_src    = (float*)alloc((size_t)N_NODES * NUM_HEADS * 4);  // 1.28 MB
  float*    s_dst    = (float*)alloc((size_t)N_NODES * NUM_HEADS * 4);  // 1.28 MB
  uint4*    perm_lg  = (uint4*)alloc((size_t)N_EDGES * 16);             // 10.24 MB
  int*      perm_src = (int*)alloc((size_t)N_EDGES * 4);                // 2.56 MB
  int*      deg      = (int*)alloc((size_t)N_NODES * 4);
  int*      rs       = (int*)alloc((size_t)(N_NODES + 1) * 4);
  int*      cursor   = (int*)alloc((size_t)N_NODES * 4);
  float*    Wfold    = (float*)alloc(NUM_HEADS * EDGE_FEATS * 4);
  float*    bfold    = (float*)alloc(NUM_HEADS * 4);
  uint32_t* Wbf      = (uint32_t*)alloc((size_t)OUT_FEATS * IN_FEATS * 2); // 64 KB

  hipMemsetAsync(deg, 0, (size_t)N_NODES * 4, stream);

  prep_hist_kernel<<<1 + N_EDGES / 512, 512, 0, stream>>>(
      edge_w, edge_b, attn, node_w, dst, Wfold, bfold, Wbf, deg);
  wh_gemm<<<N_NODES / 16 / 4, 256, 0, stream>>>(node_feats, Wbf, node_b, Whp);
  ssd_kernel<<<N_NODES * 4 / 256, 256, 0, stream>>>(Whp, attn, s_src, s_dst);
  scan_kernel<<<1, 1024, 0, stream>>>(deg, rs, cursor);
  edge_kernel<<<N_EDGES / 256, 256, 0, stream>>>(edge_feats, src, dst, Wfold,
                                                 bfold, s_src, s_dst, cursor,
                                                 perm_src, perm_lg);
  aggregate_kernel<<<N_NODES / 4, 256, 0, stream>>>(rs, perm_src, perm_lg,
                                                    Whp, out);
}

// Round 4
// 471.908 us; speedup vs baseline: 1.2540x; 1.0799x over previous
//
#include <hip/hip_runtime.h>
#include <hip/hip_fp16.h>
#include <stdint.h>
#include <stddef.h>

#define N_NODES   40000
#define N_EDGES   640000
#define IN_FEATS  256
#define EDGE_FEATS 64
#define OUT_FEATS 128
#define NUM_HEADS 8
#define HD        16   // per-head dim

typedef __attribute__((ext_vector_type(8))) short  short8;   // 8 x bf16 bits
typedef __attribute__((ext_vector_type(4))) float  floatx4;

__device__ inline short f2bf(float f) {
  union { float f; uint32_t u; } v; v.f = f;
  uint32_t r = v.u + 0x7fffu + ((v.u >> 16) & 1u);   // RNE
  return (short)(r >> 16);
}

__device__ inline short8 cvt8(float4 lo, float4 hi) {
  short8 r;
  r[0] = f2bf(lo.x); r[1] = f2bf(lo.y); r[2] = f2bf(lo.z); r[3] = f2bf(lo.w);
  r[4] = f2bf(hi.x); r[5] = f2bf(hi.y); r[6] = f2bf(hi.z); r[7] = f2bf(hi.w);
  return r;
}

__device__ inline float bflo(uint32_t w) {
  union { uint32_t u; float f; } v; v.u = w << 16; return v.f;
}
__device__ inline float bfhi(uint32_t w) {
  union { uint32_t u; float f; } v; v.u = w & 0xffff0000u; return v.f;
}

// ---------------- K1: prep (block 0: fold + W->bf16) + dst histogram
__global__ __launch_bounds__(512) void prep_hist_kernel(
    const float* __restrict__ edge_w, const float* __restrict__ edge_b,
    const float* __restrict__ attn, const float* __restrict__ node_w,
    const int* __restrict__ dst,
    float* __restrict__ Wfold, float* __restrict__ bfold,
    uint32_t* __restrict__ Wbf, int* __restrict__ deg) {
  int tid = threadIdx.x;
  if (blockIdx.x == 0) {
    int h = tid >> 6, k = tid & 63;
    float s = 0.f;
    #pragma unroll
    for (int d = 0; d < HD; d++)
      s += edge_w[(h * HD + d) * EDGE_FEATS + k] * attn[h * 48 + 32 + d];
    Wfold[h * EDGE_FEATS + k] = s;
    if (k == 0) {
      float b = 0.f;
      #pragma unroll
      for (int d = 0; d < HD; d++)
        b += edge_b[h * HD + d] * attn[h * 48 + 32 + d];
      bfold[h] = b;
    }
    const float2* W2 = (const float2*)node_w;
    #pragma unroll
    for (int j = 0; j < 32; j++) {
      int p = j * 512 + tid;
      float2 f = W2[p];
      Wbf[p] = (uint32_t)(uint16_t)f2bf(f.x) |
               ((uint32_t)(uint16_t)f2bf(f.y) << 16);
    }
  } else {
    int e = (blockIdx.x - 1) * 512 + tid;   // 1250 blocks * 512 = 640000
    atomicAdd(&deg[dst[e]], 1);
  }
}

// ---------------- K2: Whp (packed bf16) = node_feats @ node_w^T + node_b
__global__ __launch_bounds__(256) void wh_gemm(
    const float* __restrict__ A,       // node_feats [40000][256]
    const uint32_t* __restrict__ Wbf,  // node_w bf16-packed [128][256]
    const float* __restrict__ bias,    // node_b [128]
    uint32_t* __restrict__ Whp) {      // [40000][64] packed
  int wave = (blockIdx.x * blockDim.x + threadIdx.x) >> 6;
  int lane = threadIdx.x & 63;
  int m0 = wave * 16;
  if (m0 >= N_NODES) return;
  int row = lane & 15, quad = lane >> 4;

  floatx4 acc[8];
  #pragma unroll
  for (int nt = 0; nt < 8; nt++) acc[nt] = (floatx4)(0.f);

  const float4* A4 = (const float4*)A;
  const uint4*  W4 = (const uint4*)Wbf;
  int a_base = ((m0 + row) * IN_FEATS + quad * 8) >> 2;   // float4 units

  #pragma unroll
  for (int s = 0; s < 8; s++) {
    float4 alo = A4[a_base + s * 8];
    float4 ahi = A4[a_base + s * 8 + 1];
    short8 af = cvt8(alo, ahi);
    #pragma unroll
    for (int nt = 0; nt < 8; nt++) {
      int fo = (nt * 16 + row) * IN_FEATS + s * 32 + quad * 8;
      uint4 u = W4[fo >> 3];
      short8 bf = *(short8*)&u;
      acc[nt] = __builtin_amdgcn_mfma_f32_16x16x32_bf16(af, bf, acc[nt], 0, 0, 0);
    }
  }
  #pragma unroll
  for (int nt = 0; nt < 4; nt++) {
    float blo_ = bias[nt * 16 + row];
    float bhi_ = bias[64 + nt * 16 + row];
    #pragma unroll
    for (int r = 0; r < 4; r++) {
      int m = m0 + quad * 4 + r;
      float lo = acc[nt][r] + blo_;
      float hi = acc[nt + 4][r] + bhi_;
      uint32_t d = (uint32_t)(uint16_t)f2bf(lo) |
                   ((uint32_t)(uint16_t)f2bf(hi) << 16);
      Whp[m * 64 + nt * 16 + row] = d;
    }
  }
}

// ---------------- K3: s_src[n][h], s_dst[n][h] from packed Whp
__global__ __launch_bounds__(256) void ssd_kernel(
    const uint32_t* __restrict__ Whp, const float* __restrict__ attn,
    float* __restrict__ s_src, float* __restrict__ s_dst) {
  int t = blockIdx.x * 256 + threadIdx.x;   // exact 160000 = 40000*4
  int n = t >> 2, hp = t & 3;               // head pair (hp, hp+4)
  const uint4* p = (const uint4*)(Whp + n * 64 + hp * 16);
  const float* as_lo = attn + hp * 48;
  const float* ad_lo = attn + hp * 48 + 16;
  const float* as_hi = attn + (hp + 4) * 48;
  const float* ad_hi = attn + (hp + 4) * 48 + 16;
  float ss_lo = 0.f, sd_lo = 0.f, ss_hi = 0.f, sd_hi = 0.f;
  #pragma unroll
  for (int q = 0; q < 4; q++) {
    uint4 u = p[q];
    uint32_t ws[4] = {u.x, u.y, u.z, u.w};
    #pragma unroll
    for (int k = 0; k < 4; k++) {
      int d = q * 4 + k;
      float lo = bflo(ws[k]), hi = bfhi(ws[k]);
      ss_lo += lo * as_lo[d]; sd_lo += lo * ad_lo[d];
      ss_hi += hi * as_hi[d]; sd_hi += hi * ad_hi[d];
    }
  }
  s_src[n * 8 + hp]     = ss_lo;
  s_src[n * 8 + hp + 4] = ss_hi;
  s_dst[n * 8 + hp]     = sd_lo;
  s_dst[n * 8 + hp + 4] = sd_hi;
}

// ---------------- K4: chunked coalesced exclusive scan (single block)
__global__ __launch_bounds__(1024) void scan_kernel(
    const int* __restrict__ deg, int* __restrict__ rs, int* __restrict__ cursor) {
  __shared__ int wsum[16];
  __shared__ int carry;
  int tid = threadIdx.x;
  int lane = tid & 63, w = tid >> 6;
  if (tid == 0) carry = 0;
  __syncthreads();
  for (int chunk = 0; chunk < 40; chunk++) {     // 40*1024 >= 40000
    int i = chunk * 1024 + tid;
    int v = (i < N_NODES) ? deg[i] : 0;
    int x = v;
    #pragma unroll
    for (int off = 1; off < 64; off <<= 1) {
      int y = __shfl_up(x, off, 64);
      if (lane >= off) x += y;
    }
    if (lane == 63) wsum[w] = x;
    __syncthreads();                              // wsum ready
    int p = carry, tot = 0;
    #pragma unroll
    for (int j = 0; j < 16; j++) {
      int s = wsum[j];
      if (j < w) p += s;
      tot += s;
    }
    int excl = p + x - v;
    if (i < N_NODES) { rs[i] = excl; cursor[i] = excl; }
    __syncthreads();                              // all reads of wsum/carry done
    if (tid == 0) carry += tot;
  }
  __syncthreads();
  if (tid == 0) rs[N_NODES] = carry;
}

// ---------------- K5: per-edge logits, written in EDGE ORDER (coalesced)
__global__ __launch_bounds__(256) void edge_kernel(
    const float* __restrict__ edge_feats, const int* __restrict__ src,
    const int* __restrict__ dst, const float* __restrict__ Wfold,
    const float* __restrict__ bfold, const float* __restrict__ s_src,
    const float* __restrict__ s_dst, uint4* __restrict__ lg16) {
  int e = blockIdx.x * 256 + threadIdx.x;   // exact 640000
  int s = src[e], d = dst[e];
  const float4* ss4 = (const float4*)(s_src + (size_t)s * 8);
  const float4* sd4 = (const float4*)(s_dst + (size_t)d * 8);
  float4 sa = ss4[0], sb = ss4[1];
  float4 da = sd4[0], db = sd4[1];

  float acc[8];
  #pragma unroll
  for (int h = 0; h < 8; h++) acc[h] = bfold[h];
  const float4* ef4 = (const float4*)(edge_feats + (size_t)e * EDGE_FEATS);
  #pragma unroll
  for (int k4 = 0; k4 < 16; k4++) {
    float4 f = ef4[k4];
    #pragma unroll
    for (int h = 0; h < 8; h++) {
      const float* wr = Wfold + h * EDGE_FEATS + k4 * 4;  // wave-uniform
      acc[h] += f.x * wr[0] + f.y * wr[1] + f.z * wr[2] + f.w * wr[3];
    }
  }
  float v[8];
  v[0] = acc[0] + sa.x + da.x; v[1] = acc[1] + sa.y + da.y;
  v[2] = acc[2] + sa.z + da.z; v[3] = acc[3] + sa.w + da.w;
  v[4] = acc[4] + sb.x + db.x; v[5] = acc[5] + sb.y + db.y;
  v[6] = acc[6] + sb.z + db.z; v[7] = acc[7] + sb.w + db.w;
  #pragma unroll
  for (int h = 0; h < 8; h++) v[h] = v[h] > 0.f ? v[h] : 0.2f * v[h];

  uint32_t pk[4];
  #pragma unroll
  for (int j = 0; j < 4; j++) {
    uint32_t lo = __half_as_ushort(__float2half_rn(v[2 * j]));
    uint32_t hi = __half_as_ushort(__float2half_rn(v[2 * j + 1]));
    pk[j] = lo | (hi << 16);
  }
  lg16[e] = make_uint4(pk[0], pk[1], pk[2], pk[3]);   // coalesced
}

// ---------------- K6: scatter {e, src} records into CSR order (8 B)
__global__ __launch_bounds__(256) void scatter_kernel(
    const int* __restrict__ src, const int* __restrict__ dst,
    int* __restrict__ cursor, int2* __restrict__ csr8) {
  int e = blockIdx.x * 256 + threadIdx.x;   // exact 640000
  int d = dst[e];
  int s = src[e];
  int pos = atomicAdd(&cursor[d], 1);
  csr8[pos] = make_int2(e, s);
}

// ---------------- K7: per-node softmax (no-max exp) + aggregation
// 1 wave / node; lane covers output features (lane, lane+64)
__global__ __launch_bounds__(256) void aggregate_kernel(
    const int* __restrict__ rs, const int2* __restrict__ csr8,
    const uint4* __restrict__ lg16, const uint32_t* __restrict__ Whp,
    float* __restrict__ out) {
  int node = blockIdx.x * 4 + (threadIdx.x >> 6);
  int lane = threadIdx.x & 63;
  int h1 = lane >> 4;       // head of feature `lane` (0..3)
  int start = rs[node], end = rs[node + 1];
  uint32_t sh = (h1 & 1) * 16;
  bool hi_pair = (h1 & 2) != 0;

  float z1 = 0.f, z2 = 0.f, a1 = 0.f, a2 = 0.f;

  #define STEP(g, wv)                                                  \
    {                                                                  \
      uint32_t c1 = hi_pair ? (g).y : (g).x;                           \
      uint32_t c2 = hi_pair ? (g).w : (g).z;                           \
      float l1 = __half2float(__ushort_as_half((uint16_t)(c1 >> sh))); \
      float l2 = __half2float(__ushort_as_half((uint16_t)(c2 >> sh))); \
      float e1 = __expf(l1), e2 = __expf(l2);                          \
      z1 += e1; z2 += e2;                                              \
      a1 += e1 * bflo(wv); a2 += e2 * bfhi(wv);                        \
    }

  int i = start;
  for (; i + 3 < end; i += 4) {
    int2 r0 = csr8[i], r1 = csr8[i + 1], r2 = csr8[i + 2], r3 = csr8[i + 3];
    uint4 g0 = lg16[r0.x], g1 = lg16[r1.x], g2 = lg16[r2.x], g3 = lg16[r3.x];
    uint32_t w0 = Whp[(size_t)r0.y * 64 + lane];
    uint32_t w1 = Whp[(size_t)r1.y * 64 + lane];
    uint32_t w2 = Whp[(size_t)r2.y * 64 + lane];
    uint32_t w3 = Whp[(size_t)r3.y * 64 + lane];
    STEP(g0, w0); STEP(g1, w1); STEP(g2, w2); STEP(g3, w3);
  }
  for (; i < end; i++) {
    int2 r0 = csr8[i];
    uint4 g0 = lg16[r0.x];
    uint32_t w0 = Whp[(size_t)r0.y * 64 + lane];
    STEP(g0, w0);
  }
  #undef STEP

  float o1 = (end > start) ? a1 / z1 : 0.f;
  float o2 = (end > start) ? a2 / z2 : 0.f;
  out[(size_t)node * OUT_FEATS + lane] = o1;
  out[(size_t)node * OUT_FEATS + 64 + lane] = o2;
}

extern "C" void kernel_launch(void* const* d_in, const int* in_sizes, int n_in,
                              void* d_out, int out_size, void* d_ws, size_t ws_size,
                              hipStream_t stream) {
  const float* node_feats = (const float*)d_in[0];
  const float* edge_feats = (const float*)d_in[1];
  const int*   src        = (const int*)d_in[2];
  const int*   dst        = (const int*)d_in[3];
  const float* node_w     = (const float*)d_in[4];
  const float* node_b     = (const float*)d_in[5];
  const float* edge_w     = (const float*)d_in[6];
  const float* edge_b     = (const float*)d_in[7];
  const float* attn       = (const float*)d_in[8];
  float* out = (float*)d_out;

  char* ws = (char*)d_ws;
  size_t off = 0;
  auto alloc = [&](size_t bytes) {
    void* p = ws + off;
    off += (bytes + 255) & ~(size_t)255;
    return p;
  };
  uint32_t* Whp      = (uint32_t*)alloc((size_t)N_NODES * 64 * 4);      // 10.24 MB
  float*    s_src    = (float*)alloc((size_t)N_NODES * NUM_HEADS * 4);  // 1.28 MB
  float*    s_dst    = (float*)alloc((size_t)N_NODES * NUM_HEADS * 4);  // 1.28 MB
  uint4*    lg16     = (uint4*)alloc((size_t)N_EDGES * 16);             // 10.24 MB
  int2*     csr8     = (int2*)alloc((size_t)N_EDGES * 8);               // 5.12 MB
  int*      deg      = (int*)alloc((size_t)N_NODES * 4);
  int*      rs       = (int*)alloc((size_t)(N_NODES + 1) * 4);
  int*      cursor   = (int*)alloc((size_t)N_NODES * 4);
  float*    Wfold    = (float*)alloc(NUM_HEADS * EDGE_FEATS * 4);
  float*    bfold    = (float*)alloc(NUM_HEADS * 4);
  uint32_t* Wbf      = (uint32_t*)alloc((size_t)OUT_FEATS * IN_FEATS * 2); // 64 KB

  hipMemsetAsync(deg, 0, (size_t)N_NODES * 4, stream);

  prep_hist_kernel<<<1 + N_EDGES / 512, 512, 0, stream>>>(
      edge_w, edge_b, attn, node_w, dst, Wfold, bfold, Wbf, deg);
  wh_gemm<<<N_NODES / 16 / 4, 256, 0, stream>>>(node_feats, Wbf, node_b, Whp);
  ssd_kernel<<<N_NODES * 4 / 256, 256, 0, stream>>>(Whp, attn, s_src, s_dst);
  scan_kernel<<<1, 1024, 0, stream>>>(deg, rs, cursor);
  edge_kernel<<<N_EDGES / 256, 256, 0, stream>>>(edge_feats, src, dst, Wfold,
                                                 bfold, s_src, s_dst, lg16);
  scatter_kernel<<<N_EDGES / 256, 256, 0, stream>>>(src, dst, cursor, csr8);
  aggregate_kernel<<<N_NODES / 4, 256, 0, stream>>>(rs, csr8, lg16, Whp, out);
}